// Round 14
// baseline (36.498 us; speedup 1.0000x reference)
//
#include <hip/hip_runtime.h>
#include <hip/hip_fp16.h>

#define D_FEAT  128
#define PAD     16      // floats per seg_sum slot = one 64B line per node

// clang ext_vector types: accepted by __builtin_nontemporal_load/store
// (HIP_vector_type structs are not).
typedef float fv4 __attribute__((ext_vector_type(4)));
typedef int   iv4 __attribute__((ext_vector_type(4)));

// Dispatch 1: convert feats f32 -> f16 and zero the padded seg_sum slots.
// f32 source read once -> non-temporal; feats16 writes stay cached.
__global__ void convert_zero_kernel(const float* __restrict__ feats,
                                    __half* __restrict__ feats16,
                                    float* __restrict__ seg_sum,
                                    int total8, int N) {
    int i = blockIdx.x * blockDim.x + threadIdx.x;
    if (i < N) seg_sum[(size_t)i * PAD] = 0.0f;
    if (i >= total8) return;
    fv4 v0 = __builtin_nontemporal_load(((const fv4*)feats) + 2 * i);
    fv4 v1 = __builtin_nontemporal_load(((const fv4*)feats) + 2 * i + 1);
    __half2 h[4];
    h[0] = __floats2half2_rn(v0.x, v0.y);
    h[1] = __floats2half2_rn(v0.z, v0.w);
    h[2] = __floats2half2_rn(v1.x, v1.y);
    h[3] = __floats2half2_rn(v1.z, v1.w);
    ((uint4*)feats16)[i] = *reinterpret_cast<uint4*>(h);
}

__device__ inline float l1_u32(unsigned ua, unsigned ub) {
    __half2 ha = *reinterpret_cast<__half2*>(&ua);
    __half2 hb = *reinterpret_cast<__half2*>(&ub);
    float2 fa = __half22float2(ha);
    float2 fb = __half22float2(hb);
    return fabsf(fa.x - fb.x) + fabsf(fa.y - fb.y);
}
__device__ inline float l1_u4(uint4 a, uint4 b) {
    return l1_u32(a.x, b.x) + l1_u32(a.y, b.y)
         + l1_u32(a.z, b.z) + l1_u32(a.w, b.w);
}

// Dispatch 2: 16 lanes per edge (4 edges per wave64). fp16 row = 256 B =
// 16 lanes x one uint4 -> ONE vmem instruction covers a whole row (one
// 256B segment per edge per row, vs 2 with 8-lane). Halves both the
// gather-instruction count and the TA segment work per edge.
// seg_sum padded one 64B line/node (R8, -6.4us); out store non-temporal.
// seg_max pass dropped: softmax shift invariance, e in (0,1] -> exp(e)<=2.72.
__global__ void edge_eval_kernel(const __half* __restrict__ feats16,
                                 const int* __restrict__ src,
                                 const int* __restrict__ dst,
                                 float* __restrict__ seg_sum,
                                 float* __restrict__ out,
                                 int E) {
    int gtid = blockIdx.x * blockDim.x + threadIdx.x;
    int edge = gtid >> 4;
    int sl   = threadIdx.x & 15;
    if (edge >= E) return;

    int s = src[edge];
    int d = dst[edge];

    uint4 a = ((const uint4*)(feats16 + (size_t)s * D_FEAT))[sl];
    uint4 b = ((const uint4*)(feats16 + (size_t)d * D_FEAT))[sl];

    float sum = l1_u4(a, b);

    // reduce across the 16-lane group (stays within the wave)
    #pragma unroll
    for (int off = 8; off >= 1; off >>= 1)
        sum += __shfl_xor(sum, off, 64);

    if (sl == 0) {
        float p = expf(expf(-0.01f * sum));
        __builtin_nontemporal_store(p, out + edge);
        atomicAdd(seg_sum + (size_t)d * PAD, p);
    }
}

// Dispatch 3: out[e] /= seg_sum[dst[e]*PAD], 4 edges per thread.
// out/dst streams non-temporal both ways; only seg_sum gathers cache.
__global__ void edge_div_kernel(const int* __restrict__ dst,
                                const float* __restrict__ seg_sum,
                                float* __restrict__ out,
                                int E4) {
    int i = blockIdx.x * blockDim.x + threadIdx.x;
    if (i >= E4) return;
    fv4 p = __builtin_nontemporal_load(((const fv4*)out) + i);
    iv4 d = __builtin_nontemporal_load(((const iv4*)dst) + i);
    p.x /= seg_sum[(size_t)d.x * PAD];
    p.y /= seg_sum[(size_t)d.y * PAD];
    p.z /= seg_sum[(size_t)d.z * PAD];
    p.w /= seg_sum[(size_t)d.w * PAD];
    __builtin_nontemporal_store(p, ((fv4*)out) + i);
}

__global__ void edge_div_tail_kernel(const int* __restrict__ dst,
                                     const float* __restrict__ seg_sum,
                                     float* __restrict__ out,
                                     int start, int E) {
    int e = start + blockIdx.x * blockDim.x + threadIdx.x;
    if (e >= E) return;
    out[e] = out[e] / seg_sum[(size_t)dst[e] * PAD];
}

extern "C" void kernel_launch(void* const* d_in, const int* in_sizes, int n_in,
                              void* d_out, int out_size, void* d_ws, size_t ws_size,
                              hipStream_t stream) {
    const float* feats = (const float*)d_in[0];
    const int*   eidx  = (const int*)d_in[1];

    const int E = in_sizes[1] / 2;          // 320000
    const int N = in_sizes[0] / D_FEAT;     // 10000

    const int* src = eidx;       // edge_index row 0
    const int* dst = eidx + E;   // edge_index row 1

    float*  seg_sum = (float*)d_ws;                         // [N*PAD]
    __half* feats16 = (__half*)(seg_sum + (size_t)N * PAD); // [N*D]
    float*  out     = (float*)d_out;                        // [E]

    // 1) convert + zero
    {
        int total8 = N * D_FEAT / 8;   // 160000 (> N)
        dim3 blk(256);
        dim3 grd((total8 + 255) / 256);
        convert_zero_kernel<<<grd, blk, 0, stream>>>(feats, feats16,
                                                     seg_sum, total8, N);
    }
    // 2) eval: 16 lanes/edge, 16 edges/block
    {
        dim3 blk(256);
        dim3 grd((E + 15) / 16);
        edge_eval_kernel<<<grd, blk, 0, stream>>>(feats16, src, dst,
                                                  seg_sum, out, E);
    }
    // 3) divide: 4 edges/thread
    {
        int E4 = E >> 2;
        if (E4 > 0) {
            dim3 blk(256);
            dim3 grd((E4 + 255) / 256);
            edge_div_kernel<<<grd, blk, 0, stream>>>(dst, seg_sum, out, E4);
        }
        if (E & 3) {
            int start = E4 << 2;
            edge_div_tail_kernel<<<dim3(1), dim3(64), 0, stream>>>(
                dst, seg_sum, out, start, E);
        }
    }
}

// Round 15
// 34.849 us; speedup vs baseline: 1.0473x; 1.0473x over previous
//
#include <hip/hip_runtime.h>
#include <hip/hip_fp16.h>

#define D_FEAT  128
#define PAD     16      // floats per seg_sum slot = one 64B line per node

// clang ext_vector types: accepted by __builtin_nontemporal_load/store
// (HIP_vector_type structs are not).
typedef float fv4 __attribute__((ext_vector_type(4)));
typedef int   iv4 __attribute__((ext_vector_type(4)));

// Dispatch 1: convert feats f32 -> f16 and zero the padded seg_sum slots.
// Grid-stride. f32 source read once -> non-temporal; feats16 writes cached.
__global__ void __launch_bounds__(256)
convert_zero_kernel(const float* __restrict__ feats,
                    __half* __restrict__ feats16,
                    float* __restrict__ seg_sum,
                    int total8, int N) {
    int nthr = gridDim.x * blockDim.x;
    for (int i = blockIdx.x * blockDim.x + threadIdx.x; i < total8; i += nthr) {
        if (i < N) seg_sum[(size_t)i * PAD] = 0.0f;
        fv4 v0 = __builtin_nontemporal_load(((const fv4*)feats) + 2 * i);
        fv4 v1 = __builtin_nontemporal_load(((const fv4*)feats) + 2 * i + 1);
        __half2 h[4];
        h[0] = __floats2half2_rn(v0.x, v0.y);
        h[1] = __floats2half2_rn(v0.z, v0.w);
        h[2] = __floats2half2_rn(v1.x, v1.y);
        h[3] = __floats2half2_rn(v1.z, v1.w);
        ((uint4*)feats16)[i] = *reinterpret_cast<uint4*>(h);
    }
}

__device__ inline float l1_u32(unsigned ua, unsigned ub) {
    __half2 ha = *reinterpret_cast<__half2*>(&ua);
    __half2 hb = *reinterpret_cast<__half2*>(&ub);
    float2 fa = __half22float2(ha);
    float2 fb = __half22float2(hb);
    return fabsf(fa.x - fb.x) + fabsf(fa.y - fb.y);
}
__device__ inline float l1_u4(uint4 a, uint4 b) {
    return l1_u32(a.x, b.x) + l1_u32(a.y, b.y)
         + l1_u32(a.z, b.z) + l1_u32(a.w, b.w);
}

// Dispatch 2: 8 lanes per edge (8 edges per wave64), GRID-STRIDE with an
// occupancy-sized grid (2048 blocks = 8/CU) instead of 10k one-shot blocks:
// removes the command-processor launch ramp + drain from the critical path.
// fp16 rows (2x uint4/lane; 8 lanes x 16B = one 128B line per load).
// seg_sum padded one 64B line/node (R8, -6.4us); out store non-temporal.
// seg_max pass dropped: softmax shift invariance, e in (0,1] -> exp(e)<=2.72.
__global__ void __launch_bounds__(256)
edge_eval_kernel(const __half* __restrict__ feats16,
                 const int* __restrict__ src,
                 const int* __restrict__ dst,
                 float* __restrict__ seg_sum,
                 float* __restrict__ out,
                 int E) {
    int sl      = threadIdx.x & 7;
    int ngroups = (gridDim.x * blockDim.x) >> 3;
    for (int edge = (blockIdx.x * blockDim.x + threadIdx.x) >> 3;
         edge < E; edge += ngroups) {
        int s = src[edge];
        int d = dst[edge];

        const uint4* fa = (const uint4*)(feats16 + (size_t)s * D_FEAT);
        const uint4* fb = (const uint4*)(feats16 + (size_t)d * D_FEAT);
        uint4 a0 = fa[sl];
        uint4 a1 = fa[sl + 8];
        uint4 b0 = fb[sl];
        uint4 b1 = fb[sl + 8];

        float sum = l1_u4(a0, b0) + l1_u4(a1, b1);

        #pragma unroll
        for (int off = 4; off >= 1; off >>= 1)
            sum += __shfl_xor(sum, off, 64);

        if (sl == 0) {
            float p = expf(expf(-0.01f * sum));
            __builtin_nontemporal_store(p, out + edge);
            atomicAdd(seg_sum + (size_t)d * PAD, p);
        }
    }
}

// Dispatch 3: out[e] /= seg_sum[dst[e]*PAD], 4 edges/thread, grid-stride.
// out/dst streams non-temporal both ways; only seg_sum gathers cache.
__global__ void __launch_bounds__(256)
edge_div_kernel(const int* __restrict__ dst,
                const float* __restrict__ seg_sum,
                float* __restrict__ out,
                int E4) {
    int nthr = gridDim.x * blockDim.x;
    for (int i = blockIdx.x * blockDim.x + threadIdx.x; i < E4; i += nthr) {
        fv4 p = __builtin_nontemporal_load(((const fv4*)out) + i);
        iv4 d = __builtin_nontemporal_load(((const iv4*)dst) + i);
        p.x /= seg_sum[(size_t)d.x * PAD];
        p.y /= seg_sum[(size_t)d.y * PAD];
        p.z /= seg_sum[(size_t)d.z * PAD];
        p.w /= seg_sum[(size_t)d.w * PAD];
        __builtin_nontemporal_store(p, ((fv4*)out) + i);
    }
}

__global__ void edge_div_tail_kernel(const int* __restrict__ dst,
                                     const float* __restrict__ seg_sum,
                                     float* __restrict__ out,
                                     int start, int E) {
    int e = start + blockIdx.x * blockDim.x + threadIdx.x;
    if (e >= E) return;
    out[e] = out[e] / seg_sum[(size_t)dst[e] * PAD];
}

extern "C" void kernel_launch(void* const* d_in, const int* in_sizes, int n_in,
                              void* d_out, int out_size, void* d_ws, size_t ws_size,
                              hipStream_t stream) {
    const float* feats = (const float*)d_in[0];
    const int*   eidx  = (const int*)d_in[1];

    const int E = in_sizes[1] / 2;          // 320000
    const int N = in_sizes[0] / D_FEAT;     // 10000

    const int* src = eidx;       // edge_index row 0
    const int* dst = eidx + E;   // edge_index row 1

    float*  seg_sum = (float*)d_ws;                         // [N*PAD]
    __half* feats16 = (__half*)(seg_sum + (size_t)N * PAD); // [N*D]
    float*  out     = (float*)d_out;                        // [E]

    // 1) convert + zero (grid-stride, 625 blocks covers total8 in one pass)
    {
        int total8 = N * D_FEAT / 8;   // 160000 (> N)
        dim3 blk(256);
        dim3 grd((total8 + 255) / 256);
        convert_zero_kernel<<<grd, blk, 0, stream>>>(feats, feats16,
                                                     seg_sum, total8, N);
    }
    // 2) eval: 8 lanes/edge, grid-stride over edges, 2048 blocks (8/CU)
    {
        int needed = (E + 31) / 32;               // blocks for one pass
        int grid   = needed < 2048 ? needed : 2048;
        edge_eval_kernel<<<dim3(grid), dim3(256), 0, stream>>>(
            feats16, src, dst, seg_sum, out, E);
    }
    // 3) divide: 4 edges/thread, grid-stride, capped at 1024 blocks
    {
        int E4 = E >> 2;
        if (E4 > 0) {
            int needed = (E4 + 255) / 256;
            int grid   = needed < 1024 ? needed : 1024;
            edge_div_kernel<<<dim3(grid), dim3(256), 0, stream>>>(
                dst, seg_sum, out, E4);
        }
        if (E & 3) {
            int start = E4 << 2;
            edge_div_tail_kernel<<<dim3(1), dim3(64), 0, stream>>>(
                dst, seg_sum, out, start, E);
        }
    }
}

// Round 16
// 34.818 us; speedup vs baseline: 1.0482x; 1.0009x over previous
//
#include <hip/hip_runtime.h>
#include <hip/hip_fp16.h>

#define D_FEAT  128
#define PAD     16      // floats per seg_sum slot = one 64B line per node

// clang ext_vector types: accepted by __builtin_nontemporal_load/store
// (HIP_vector_type structs are not).
typedef float fv4 __attribute__((ext_vector_type(4)));
typedef int   iv4 __attribute__((ext_vector_type(4)));

// Dispatch 1: convert feats f32 -> f16 and zero the padded seg_sum slots.
// f32 source read once -> non-temporal; feats16 writes stay cached.
__global__ void convert_zero_kernel(const float* __restrict__ feats,
                                    __half* __restrict__ feats16,
                                    float* __restrict__ seg_sum,
                                    int total8, int N) {
    int i = blockIdx.x * blockDim.x + threadIdx.x;
    if (i < N) seg_sum[(size_t)i * PAD] = 0.0f;
    if (i >= total8) return;
    fv4 v0 = __builtin_nontemporal_load(((const fv4*)feats) + 2 * i);
    fv4 v1 = __builtin_nontemporal_load(((const fv4*)feats) + 2 * i + 1);
    __half2 h[4];
    h[0] = __floats2half2_rn(v0.x, v0.y);
    h[1] = __floats2half2_rn(v0.z, v0.w);
    h[2] = __floats2half2_rn(v1.x, v1.y);
    h[3] = __floats2half2_rn(v1.z, v1.w);
    ((uint4*)feats16)[i] = *reinterpret_cast<uint4*>(h);
}

__device__ inline float l1_u32(unsigned ua, unsigned ub) {
    __half2 ha = *reinterpret_cast<__half2*>(&ua);
    __half2 hb = *reinterpret_cast<__half2*>(&ub);
    float2 fa = __half22float2(ha);
    float2 fb = __half22float2(hb);
    return fabsf(fa.x - fb.x) + fabsf(fa.y - fb.y);
}
__device__ inline float l1_u4(uint4 a, uint4 b) {
    return l1_u32(a.x, b.x) + l1_u32(a.y, b.y)
         + l1_u32(a.z, b.z) + l1_u32(a.w, b.w);
}

// Dispatch 2: 8 lanes per edge (8 edges per wave64), fp16 rows (2x uint4 per
// lane; 8 lanes x 16B = one 128B line per load). Index streams and out store
// are NON-TEMPORAL (read/written once); only the feats16 table + seg_sum
// lines stay cached. seg_sum padded one 64B line/node (R8, -6.4us).
// seg_max pass dropped: softmax shift invariance, e in (0,1] -> exp(e)<=2.72.
__global__ void edge_eval_kernel(const __half* __restrict__ feats16,
                                 const int* __restrict__ src,
                                 const int* __restrict__ dst,
                                 float* __restrict__ seg_sum,
                                 float* __restrict__ out,
                                 int E) {
    int gtid = blockIdx.x * blockDim.x + threadIdx.x;
    int edge = gtid >> 3;
    int sl   = threadIdx.x & 7;
    if (edge >= E) return;

    int s = __builtin_nontemporal_load(src + edge);
    int d = __builtin_nontemporal_load(dst + edge);

    const uint4* fa = (const uint4*)(feats16 + (size_t)s * D_FEAT);
    const uint4* fb = (const uint4*)(feats16 + (size_t)d * D_FEAT);
    uint4 a0 = fa[sl];
    uint4 a1 = fa[sl + 8];
    uint4 b0 = fb[sl];
    uint4 b1 = fb[sl + 8];

    float sum = l1_u4(a0, b0) + l1_u4(a1, b1);

    #pragma unroll
    for (int off = 4; off >= 1; off >>= 1)
        sum += __shfl_xor(sum, off, 64);

    if (sl == 0) {
        float p = expf(expf(-0.01f * sum));
        __builtin_nontemporal_store(p, out + edge);
        atomicAdd(seg_sum + (size_t)d * PAD, p);
    }
}

// Dispatch 3: out[e] /= seg_sum[dst[e]*PAD], 4 edges per thread.
// out/dst streams non-temporal both ways; only seg_sum gathers cache.
__global__ void edge_div_kernel(const int* __restrict__ dst,
                                const float* __restrict__ seg_sum,
                                float* __restrict__ out,
                                int E4) {
    int i = blockIdx.x * blockDim.x + threadIdx.x;
    if (i >= E4) return;
    fv4 p = __builtin_nontemporal_load(((const fv4*)out) + i);
    iv4 d = __builtin_nontemporal_load(((const iv4*)dst) + i);
    p.x /= seg_sum[(size_t)d.x * PAD];
    p.y /= seg_sum[(size_t)d.y * PAD];
    p.z /= seg_sum[(size_t)d.z * PAD];
    p.w /= seg_sum[(size_t)d.w * PAD];
    __builtin_nontemporal_store(p, ((fv4*)out) + i);
}

__global__ void edge_div_tail_kernel(const int* __restrict__ dst,
                                     const float* __restrict__ seg_sum,
                                     float* __restrict__ out,
                                     int start, int E) {
    int e = start + blockIdx.x * blockDim.x + threadIdx.x;
    if (e >= E) return;
    out[e] = out[e] / seg_sum[(size_t)dst[e] * PAD];
}

extern "C" void kernel_launch(void* const* d_in, const int* in_sizes, int n_in,
                              void* d_out, int out_size, void* d_ws, size_t ws_size,
                              hipStream_t stream) {
    const float* feats = (const float*)d_in[0];
    const int*   eidx  = (const int*)d_in[1];

    const int E = in_sizes[1] / 2;          // 320000
    const int N = in_sizes[0] / D_FEAT;     // 10000

    const int* src = eidx;       // edge_index row 0
    const int* dst = eidx + E;   // edge_index row 1

    float*  seg_sum = (float*)d_ws;                         // [N*PAD]
    __half* feats16 = (__half*)(seg_sum + (size_t)N * PAD); // [N*D]
    float*  out     = (float*)d_out;                        // [E]

    // 1) convert + zero
    {
        int total8 = N * D_FEAT / 8;   // 160000 (> N)
        dim3 blk(256);
        dim3 grd((total8 + 255) / 256);
        convert_zero_kernel<<<grd, blk, 0, stream>>>(feats, feats16,
                                                     seg_sum, total8, N);
    }
    // 2) eval: 8 lanes/edge, 32 edges/block
    {
        dim3 blk(256);
        dim3 grd((E + 31) / 32);
        edge_eval_kernel<<<grd, blk, 0, stream>>>(feats16, src, dst,
                                                  seg_sum, out, E);
    }
    // 3) divide: 4 edges/thread
    {
        int E4 = E >> 2;
        if (E4 > 0) {
            dim3 blk(256);
            dim3 grd((E4 + 255) / 256);
            edge_div_kernel<<<grd, blk, 0, stream>>>(dst, seg_sum, out, E4);
        }
        if (E & 3) {
            int start = E4 << 2;
            edge_div_tail_kernel<<<dim3(1), dim3(64), 0, stream>>>(
                dst, seg_sum, out, start, E);
        }
    }
}

// Round 17
// 34.580 us; speedup vs baseline: 1.0554x; 1.0069x over previous
//
#include <hip/hip_runtime.h>
#include <hip/hip_fp16.h>

#define D_FEAT  128
#define PAD     16      // floats per seg_sum slot = one 64B line per node

// clang ext_vector types: accepted by __builtin_nontemporal_load/store
// (HIP_vector_type structs are not).
typedef float fv4 __attribute__((ext_vector_type(4)));
typedef int   iv4 __attribute__((ext_vector_type(4)));

// Dispatch 1: convert feats f32 -> f16 and zero the padded seg_sum slots.
// f32 source read once -> non-temporal; feats16 writes stay cached.
__global__ void convert_zero_kernel(const float* __restrict__ feats,
                                    __half* __restrict__ feats16,
                                    float* __restrict__ seg_sum,
                                    int total8, int N) {
    int i = blockIdx.x * blockDim.x + threadIdx.x;
    if (i < N) seg_sum[(size_t)i * PAD] = 0.0f;
    if (i >= total8) return;
    fv4 v0 = __builtin_nontemporal_load(((const fv4*)feats) + 2 * i);
    fv4 v1 = __builtin_nontemporal_load(((const fv4*)feats) + 2 * i + 1);
    __half2 h[4];
    h[0] = __floats2half2_rn(v0.x, v0.y);
    h[1] = __floats2half2_rn(v0.z, v0.w);
    h[2] = __floats2half2_rn(v1.x, v1.y);
    h[3] = __floats2half2_rn(v1.z, v1.w);
    ((uint4*)feats16)[i] = *reinterpret_cast<uint4*>(h);
}

__device__ inline float l1_u32(unsigned ua, unsigned ub) {
    __half2 ha = *reinterpret_cast<__half2*>(&ua);
    __half2 hb = *reinterpret_cast<__half2*>(&ub);
    float2 fa = __half22float2(ha);
    float2 fb = __half22float2(hb);
    return fabsf(fa.x - fb.x) + fabsf(fa.y - fb.y);
}
__device__ inline float l1_u4(uint4 a, uint4 b) {
    return l1_u32(a.x, b.x) + l1_u32(a.y, b.y)
         + l1_u32(a.z, b.z) + l1_u32(a.w, b.w);
}

// Dispatch 2: 8 lanes per edge (8 edges per wave64), fp16 rows (2x uint4 per
// lane; 8 lanes x 16B = one 128B line per load). out store is NON-TEMPORAL:
// the 1.28 MB stream must not evict the L2-resident feats16 table.
// Index loads stay cached (shared across the 8-lane group via L1).
// seg_sum padded one 64B line/node (R8, -6.4us). seg_max pass dropped:
// softmax shift invariance, e = exp(-0.01*L1) in (0,1] -> exp(e) <= 2.72.
__global__ void edge_eval_kernel(const __half* __restrict__ feats16,
                                 const int* __restrict__ src,
                                 const int* __restrict__ dst,
                                 float* __restrict__ seg_sum,
                                 float* __restrict__ out,
                                 int E) {
    int gtid = blockIdx.x * blockDim.x + threadIdx.x;
    int edge = gtid >> 3;
    int sl   = threadIdx.x & 7;
    if (edge >= E) return;

    int s = src[edge];
    int d = dst[edge];

    const uint4* fa = (const uint4*)(feats16 + (size_t)s * D_FEAT);
    const uint4* fb = (const uint4*)(feats16 + (size_t)d * D_FEAT);
    uint4 a0 = fa[sl];
    uint4 a1 = fa[sl + 8];
    uint4 b0 = fb[sl];
    uint4 b1 = fb[sl + 8];

    float sum = l1_u4(a0, b0) + l1_u4(a1, b1);

    #pragma unroll
    for (int off = 4; off >= 1; off >>= 1)
        sum += __shfl_xor(sum, off, 64);

    if (sl == 0) {
        float p = expf(expf(-0.01f * sum));
        __builtin_nontemporal_store(p, out + edge);
        atomicAdd(seg_sum + (size_t)d * PAD, p);
    }
}

// Dispatch 3: out[e] /= seg_sum[dst[e]*PAD], 4 edges per thread.
// out/dst streams non-temporal both ways; only seg_sum gathers cache.
__global__ void edge_div_kernel(const int* __restrict__ dst,
                                const float* __restrict__ seg_sum,
                                float* __restrict__ out,
                                int E4) {
    int i = blockIdx.x * blockDim.x + threadIdx.x;
    if (i >= E4) return;
    fv4 p = __builtin_nontemporal_load(((const fv4*)out) + i);
    iv4 d = __builtin_nontemporal_load(((const iv4*)dst) + i);
    p.x /= seg_sum[(size_t)d.x * PAD];
    p.y /= seg_sum[(size_t)d.y * PAD];
    p.z /= seg_sum[(size_t)d.z * PAD];
    p.w /= seg_sum[(size_t)d.w * PAD];
    __builtin_nontemporal_store(p, ((fv4*)out) + i);
}

__global__ void edge_div_tail_kernel(const int* __restrict__ dst,
                                     const float* __restrict__ seg_sum,
                                     float* __restrict__ out,
                                     int start, int E) {
    int e = start + blockIdx.x * blockDim.x + threadIdx.x;
    if (e >= E) return;
    out[e] = out[e] / seg_sum[(size_t)dst[e] * PAD];
}

extern "C" void kernel_launch(void* const* d_in, const int* in_sizes, int n_in,
                              void* d_out, int out_size, void* d_ws, size_t ws_size,
                              hipStream_t stream) {
    const float* feats = (const float*)d_in[0];
    const int*   eidx  = (const int*)d_in[1];

    const int E = in_sizes[1] / 2;          // 320000
    const int N = in_sizes[0] / D_FEAT;     // 10000

    const int* src = eidx;       // edge_index row 0
    const int* dst = eidx + E;   // edge_index row 1

    float*  seg_sum = (float*)d_ws;                         // [N*PAD]
    __half* feats16 = (__half*)(seg_sum + (size_t)N * PAD); // [N*D]
    float*  out     = (float*)d_out;                        // [E]

    // 1) convert + zero
    {
        int total8 = N * D_FEAT / 8;   // 160000 (> N)
        dim3 blk(256);
        dim3 grd((total8 + 255) / 256);
        convert_zero_kernel<<<grd, blk, 0, stream>>>(feats, feats16,
                                                     seg_sum, total8, N);
    }
    // 2) eval: 8 lanes/edge, 32 edges/block
    {
        dim3 blk(256);
        dim3 grd((E + 31) / 32);
        edge_eval_kernel<<<grd, blk, 0, stream>>>(feats16, src, dst,
                                                  seg_sum, out, E);
    }
    // 3) divide: 4 edges/thread
    {
        int E4 = E >> 2;
        if (E4 > 0) {
            dim3 blk(256);
            dim3 grd((E4 + 255) / 256);
            edge_div_kernel<<<grd, blk, 0, stream>>>(dst, seg_sum, out, E4);
        }
        if (E & 3) {
            int start = E4 << 2;
            edge_div_tail_kernel<<<dim3(1), dim3(64), 0, stream>>>(
                dst, seg_sum, out, start, E);
        }
    }
}